// Round 5
// baseline (4526.487 us; speedup 1.0000x reference)
//
#include <hip/hip_runtime.h>
#include <hip/hip_bf16.h>

#define RROWS 4096
#define HID   512
#define VOC   32000
#define TOPK  300
#define NBINS 8192
#define CAP   2048

// ---------------- 1) transpose W [HID][VOC] -> [VOC][HID] --------------------
__global__ __launch_bounds__(256) void k_transpose(const float* __restrict__ in,
                                                   float* __restrict__ outT) {
  __shared__ float tile[32][33];
  const int bx = blockIdx.x, by = blockIdx.y;
  const int x = bx * 32 + threadIdx.x;   // v
  const int y0 = by * 32;                // h base
#pragma unroll
  for (int i = 0; i < 32; i += 8)
    tile[threadIdx.y + i][threadIdx.x] = in[(size_t)(y0 + threadIdx.y + i) * VOC + x];
  __syncthreads();
  const int xo = by * 32 + threadIdx.x;  // h
  const int yo = bx * 32;                // v base
#pragma unroll
  for (int i = 0; i < 32; i += 8)
    outT[(size_t)(yo + threadIdx.y + i) * HID + xo] = tile[threadIdx.x][threadIdx.y + i];
}

// ---------------- 2) f32 tiled GEMM: hi = hs @ W_bin (binning proxy only) ----
#define BM 64
#define BN 64
#define BK 16
__global__ __launch_bounds__(256) void k_score(const float* __restrict__ A,
                                               const float* __restrict__ B,
                                               float* __restrict__ hi) {
  __shared__ float As[BK][BM];
  __shared__ float Bs[BK][BN];
  const int t  = threadIdx.x;
  const int tx = t & 15, ty = t >> 4;
  const int bx = blockIdx.x, by = blockIdx.y;
  const int arow = t >> 2, acg = t & 3;
  const int brow = t >> 4, bcg = t & 15;
  const float* Ap = A + (size_t)(by * BM + arow) * HID + acg * 4;
  const float* Bp = B + (size_t)brow * VOC + (size_t)bx * BN + bcg * 4;

  float acc[4][4] = {};
  for (int k0 = 0; k0 < HID; k0 += BK) {
    const float4 av = *(const float4*)(Ap + k0);
    const float4 bv = *(const float4*)(Bp + (size_t)k0 * VOC);
    As[acg * 4 + 0][arow] = av.x;
    As[acg * 4 + 1][arow] = av.y;
    As[acg * 4 + 2][arow] = av.z;
    As[acg * 4 + 3][arow] = av.w;
    *(float4*)&Bs[brow][bcg * 4] = bv;
    __syncthreads();
#pragma unroll
    for (int kk = 0; kk < BK; ++kk) {
      const float4 af = *(const float4*)&As[kk][ty * 4];
      const float4 bf = *(const float4*)&Bs[kk][tx * 4];
#pragma unroll
      for (int i = 0; i < 4; ++i) {
        const float a = (&af.x)[i];
        acc[i][0] += a * bf.x; acc[i][1] += a * bf.y;
        acc[i][2] += a * bf.z; acc[i][3] += a * bf.w;
      }
    }
    __syncthreads();
  }
  const size_t colbase = (size_t)bx * BN + tx * 4;
#pragma unroll
  for (int i = 0; i < 4; ++i) {
    const size_t row = (size_t)by * BM + ty * 4 + i;
    *(float4*)(hi + row * VOC + colbase) =
        make_float4(acc[i][0], acc[i][1], acc[i][2], acc[i][3]);
  }
}

// ---------------- XLA/Eigen f32 fast-tanh rational approximation -------------
// Matches XLA's EmitTanh lowering: clamp, |x|<4e-4 passthrough, fma-Horner
// numerator/denominator, IEEE correctly-rounded divide.
__device__ __forceinline__ float tanh_xla(float x) {
  const float ax = fabsf(x);
  const float cx = fminf(fmaxf(x, -9.0f), 9.0f);
  const float x2 = cx * cx;
  float p = -2.76076847742355e-16f;
  p = fmaf(x2, p, 2.00018790482477e-13f);
  p = fmaf(x2, p, -8.60467152213735e-11f);
  p = fmaf(x2, p, 5.12229709037114e-08f);
  p = fmaf(x2, p, 1.48572235717979e-05f);
  p = fmaf(x2, p, 6.37261928875436e-04f);
  p = fmaf(x2, p, 4.89352455891786e-03f);
  p = cx * p;
  float q = 1.19825839466702e-06f;
  q = fmaf(x2, q, 1.18534705686654e-04f);
  q = fmaf(x2, q, 2.26843463243900e-03f);
  q = fmaf(x2, q, 4.89352518554385e-03f);
  const float r = p / q;
  return (ax < 0.0004f) ? x : r;
}

// ------- 3) per-row top-300 by f32 tanh(tanh(x_chain)), ties -> low idx ------
__device__ __forceinline__ unsigned sortable_u32(float x) {
  unsigned u = __float_as_uint(x);
  return (u & 0x80000000u) ? ~u : (u | 0x80000000u);
}

__global__ __launch_bounds__(256) void k_topk(const float* __restrict__ hs,
                                              const float* __restrict__ Wb,
                                              const float* __restrict__ WbT,
                                              const float* __restrict__ hi,
                                              float* __restrict__ oidx) {
  const int r = blockIdx.x;
  const int t = threadIdx.x;
  const float* rh = hi + (size_t)r * VOC;

  __shared__ unsigned hist[NBINS];
  __shared__ unsigned partial[256];
  __shared__ float    hrow[HID];
  __shared__ float    vals[CAP];
  __shared__ int      idxs[CAP];
  __shared__ unsigned cnt;
  __shared__ int      bLo_s;

  for (int i = t; i < HID; i += 256) hrow[i] = hs[(size_t)r * HID + i];
  for (int i = t; i < NBINS; i += 256) hist[i] = 0u;
  if (t == 0) cnt = 0u;
  __syncthreads();

  for (int v = t; v < VOC; v += 256)
    atomicAdd(&hist[sortable_u32(rh[v]) >> 19], 1u);
  __syncthreads();

  // suffix scan over 256 chunks of 32 bins
  unsigned psum = 0;
#pragma unroll
  for (int i = 0; i < NBINS / 256; ++i) psum += hist[t * (NBINS / 256) + i];
  partial[t] = psum;
  __syncthreads();
  for (int off = 1; off < 256; off <<= 1) {
    const unsigned add = (t + off < 256) ? partial[t + off] : 0u;
    __syncthreads();
    partial[t] += add;
    __syncthreads();
  }
  const unsigned above = partial[t] - psum;  // count in chunks above t
  if (above < TOPK && partial[t] >= TOPK) {  // crossing chunk (exactly one t)
    unsigned c = above;
    int b = t * (NBINS / 256);
    for (int i = NBINS / 256 - 1; i >= 0; --i) {
      c += hist[t * (NBINS / 256) + i];
      if (c >= TOPK) { b = t * (NBINS / 256) + i; break; }
    }
    // extend 2 safety bins below (covers |hi - chain x| slack; y monotone in x)
    int bl = b;
    unsigned tot = c;
    for (int s = 0; s < 2; ++s) {
      if (bl > 0 && tot + hist[bl - 1] <= (unsigned)CAP) { tot += hist[bl - 1]; --bl; }
    }
    bLo_s = bl;
  }
  __syncthreads();
  const int bLo = bLo_s;

  // collect candidate indices
  for (int v = t; v < VOC; v += 256) {
    if ((int)(sortable_u32(rh[v]) >> 19) >= bLo) {
      const unsigned p = atomicAdd(&cnt, 1u);
      if (p < CAP) idxs[p] = v;
    }
  }
  __syncthreads();
  const int n = (int)min(cnt, (unsigned)CAP);

  // x = ascending-k single-accumulator fmaf chain (BLAS-microkernel order),
  // then the reference's double f32 tanh quantization. Rank by y.
  for (int k = t; k < n; k += 256) {
    const int c = idxs[k];
    float acc = 0.0f;
    if (WbT) {
      const float* w = WbT + (size_t)c * HID;
      for (int h = 0; h < HID; ++h) acc = fmaf(hrow[h], w[h], acc);
    } else {
      for (int h = 0; h < HID; ++h) acc = fmaf(hrow[h], Wb[(size_t)h * VOC + c], acc);
    }
    vals[k] = tanh_xla(tanh_xla(acc));
  }
  __syncthreads();
  for (int i = t; i < CAP; i += 256) {
    if (i >= n) { vals[i] = -3.0e38f; idxs[i] = 0x7FFFFFFF; }
  }
  __syncthreads();

  // bitonic sort: y desc, tie -> lower index (lax.top_k / stable argsort order)
  for (int k = 2; k <= CAP; k <<= 1) {
    for (int j = k >> 1; j > 0; j >>= 1) {
      for (int i = t; i < CAP; i += 256) {
        const int l = i ^ j;
        if (l > i) {
          const float vi = vals[i], vl = vals[l];
          const int   ii = idxs[i], il = idxs[l];
          const bool up = ((i & k) == 0);
          const bool lBetter = (vl > vi) || (vl == vi && il < ii);
          const bool iBetter = (vi > vl) || (vi == vl && ii < il);
          if (up ? lBetter : iBetter) {
            vals[i] = vl; vals[l] = vi;
            idxs[i] = il; idxs[l] = ii;
          }
        }
      }
      __syncthreads();
    }
  }
  for (int j = t; j < TOPK; j += 256)
    oidx[(size_t)r * TOPK + j] = (float)idxs[j];
}

// ------- 4) zero row, compute candidate logits vs W_out (f64), scatter -------
__global__ __launch_bounds__(256) void k_scatter(const float* __restrict__ hs,
                                                 const float* __restrict__ wout,
                                                 const float* __restrict__ woutT,
                                                 const float* __restrict__ oidx,
                                                 float* __restrict__ out) {
  const int r = blockIdx.x;
  const int t = threadIdx.x;
  __shared__ float hrow[HID];
  __shared__ int   cidx[TOPK];
  __shared__ float cval[TOPK];

  for (int i = t; i < HID; i += 256) hrow[i] = hs[(size_t)r * HID + i];
  for (int i = t; i < TOPK; i += 256) cidx[i] = (int)(oidx[(size_t)r * TOPK + i] + 0.5f);
  __syncthreads();

  float* orow = out + (size_t)r * VOC;
  const float4 z4 = make_float4(0.f, 0.f, 0.f, 0.f);
  for (int i = t; i < VOC / 4; i += 256) ((float4*)orow)[i] = z4;

  const int lane = t & 63, wave = t >> 6;
  double ha[8];
#pragma unroll
  for (int u = 0; u < 8; ++u) ha[u] = (double)hrow[lane * 8 + u];

  for (int k = wave; k < TOPK; k += 4) {
    const int c = cidx[k];
    double s = 0.0;
    if (woutT) {
      const float4* col = (const float4*)(woutT + (size_t)c * HID + lane * 8);
      const float4 w0 = col[0], w1 = col[1];
      s = ha[0] * (double)w0.x + ha[1] * (double)w0.y + ha[2] * (double)w0.z + ha[3] * (double)w0.w
        + ha[4] * (double)w1.x + ha[5] * (double)w1.y + ha[6] * (double)w1.z + ha[7] * (double)w1.w;
    } else {
#pragma unroll
      for (int u = 0; u < 8; ++u)
        s += ha[u] * (double)wout[(size_t)(lane * 8 + u) * VOC + c];
    }
#pragma unroll
    for (int off = 32; off > 0; off >>= 1) s += __shfl_down(s, off);
    if (lane == 0) cval[k] = (float)s;
  }
  __syncthreads();
  for (int j = t; j < TOPK; j += 256) orow[cidx[j]] = cval[j];
}

// -----------------------------------------------------------------------------
extern "C" void kernel_launch(void* const* d_in, const int* in_sizes, int n_in,
                              void* d_out, int out_size, void* d_ws, size_t ws_size,
                              hipStream_t stream) {
  const float* hs    = (const float*)d_in[0];
  const float* W_out = (const float*)d_in[1];
  const float* W_bin = (const float*)d_in[2];
  float* out  = (float*)d_out;
  float* hi   = out;                        // logits region doubles as score scratch
  float* oidx = out + (size_t)RROWS * VOC;  // indices (stored as float)

  const size_t needT = (size_t)VOC * HID * sizeof(float);  // 65.5 MB per transpose
  float* wbT = nullptr;
  float* woT = nullptr;
  if (ws_size >= needT)     wbT = (float*)d_ws;
  if (ws_size >= 2 * needT) woT = (float*)d_ws + (size_t)VOC * HID;

  if (wbT) k_transpose<<<dim3(VOC / 32, HID / 32), dim3(32, 8), 0, stream>>>(W_bin, wbT);
  if (woT) k_transpose<<<dim3(VOC / 32, HID / 32), dim3(32, 8), 0, stream>>>(W_out, woT);
  k_score<<<dim3(VOC / BN, RROWS / BM), 256, 0, stream>>>(hs, W_bin, hi);
  k_topk<<<RROWS, 256, 0, stream>>>(hs, W_bin, wbT, hi, oidx);
  k_scatter<<<RROWS, 256, 0, stream>>>(hs, W_out, woT, oidx, out);
}

// Round 7
// 2313.320 us; speedup vs baseline: 1.9567x; 1.9567x over previous
//
#include <hip/hip_runtime.h>
#include <hip/hip_bf16.h>

#define RROWS 4096
#define HID   512
#define VOC   32000
#define TOPK  300
#define NBINS 8192
#define CAP   2048

typedef __attribute__((ext_vector_type(8))) short  bf16x8;
typedef __attribute__((ext_vector_type(4))) float  f32x4;
typedef __attribute__((ext_vector_type(8))) unsigned short u16x8;

__device__ __forceinline__ unsigned short f32_to_bf16(float f) {
  union { float f; unsigned u; } v; v.f = f;
  const unsigned r = v.u + 0x7FFFu + ((v.u >> 16) & 1u);  // RNE
  return (unsigned short)(r >> 16);
}

// ---------------- 1) transpose W [HID][VOC] -> [VOC][HID] (f32) --------------
__global__ __launch_bounds__(256) void k_transpose(const float* __restrict__ in,
                                                   float* __restrict__ outT) {
  __shared__ float tile[32][33];
  const int bx = blockIdx.x, by = blockIdx.y;
  const int x = bx * 32 + threadIdx.x;
  const int y0 = by * 32;
#pragma unroll
  for (int i = 0; i < 32; i += 8)
    tile[threadIdx.y + i][threadIdx.x] = in[(size_t)(y0 + threadIdx.y + i) * VOC + x];
  __syncthreads();
  const int xo = by * 32 + threadIdx.x;
  const int yo = bx * 32;
#pragma unroll
  for (int i = 0; i < 32; i += 8)
    outT[(size_t)(yo + threadIdx.y + i) * HID + xo] = tile[threadIdx.x][threadIdx.y + i];
}

// ---------------- cvt helpers ------------------------------------------------
__global__ __launch_bounds__(256) void k_cvt(const float* __restrict__ in,
                                             unsigned short* __restrict__ out, int n4) {
  const int i = blockIdx.x * 256 + threadIdx.x;  // n4 = n/4
  if (i < n4) {
    const float4 v = ((const float4*)in)[i];
    out[i * 4 + 0] = f32_to_bf16(v.x);
    out[i * 4 + 1] = f32_to_bf16(v.y);
    out[i * 4 + 2] = f32_to_bf16(v.z);
    out[i * 4 + 3] = f32_to_bf16(v.w);
  }
}

// ---------------- 2a) bf16 MFMA GEMM: hib = bf16(hs) @ bf16(W_bin) -----------
// A [RROWS][HID] bf16, B^T [VOC][HID] bf16, C -> bf16 [RROWS][VOC].
#define GBM 128
#define GBN 128
#define GBK 32
#define LDK 40   // padded LDS K-stride (elems); 80 B rows keep 16B alignment
__global__ __launch_bounds__(256) void k_score_mfma(const unsigned short* __restrict__ Ab,
                                                    const unsigned short* __restrict__ Bb,
                                                    unsigned short* __restrict__ hib) {
  __shared__ unsigned short As[GBM * LDK];
  __shared__ unsigned short Bs[GBN * LDK];
  const int t = threadIdx.x;
  const int bx = blockIdx.x;  // N tile (250)
  const int by = blockIdx.y;  // M tile (32)
  const int l = t & 63, w = t >> 6;
  const int wr = w >> 1, wc = w & 1;

  const int srow = t >> 2;         // 0..63
  const int scol = (t & 3) * 8;    // 0,8,16,24
  const size_t abase = ((size_t)by * GBM + srow) * HID + scol;
  const size_t bbase = ((size_t)bx * GBN + srow) * HID + scol;

  f32x4 acc[4][4] = {};
  for (int k0 = 0; k0 < HID; k0 += GBK) {
    *(bf16x8*)&As[srow * LDK + scol]        = *(const bf16x8*)&Ab[abase + k0];
    *(bf16x8*)&As[(srow + 64) * LDK + scol] = *(const bf16x8*)&Ab[abase + (size_t)64 * HID + k0];
    *(bf16x8*)&Bs[srow * LDK + scol]        = *(const bf16x8*)&Bb[bbase + k0];
    *(bf16x8*)&Bs[(srow + 64) * LDK + scol] = *(const bf16x8*)&Bb[bbase + (size_t)64 * HID + k0];
    __syncthreads();
    const int fr = l & 15, kq = (l >> 4) * 8;
    bf16x8 af[4], bfr[4];
#pragma unroll
    for (int i = 0; i < 4; ++i)
      af[i] = *(const bf16x8*)&As[(wr * 64 + i * 16 + fr) * LDK + kq];
#pragma unroll
    for (int j = 0; j < 4; ++j)
      bfr[j] = *(const bf16x8*)&Bs[(wc * 64 + j * 16 + fr) * LDK + kq];
#pragma unroll
    for (int i = 0; i < 4; ++i)
#pragma unroll
      for (int j = 0; j < 4; ++j)
        acc[i][j] = __builtin_amdgcn_mfma_f32_16x16x32_bf16(af[i], bfr[j], acc[i][j], 0, 0, 0);
    __syncthreads();
  }
  // C/D mapping (m89-verified): col = lane&15, row = (lane>>4)*4 + reg
  const int fn = l & 15, fq = l >> 4;
#pragma unroll
  for (int i = 0; i < 4; ++i)
#pragma unroll
    for (int j = 0; j < 4; ++j)
#pragma unroll
      for (int rg = 0; rg < 4; ++rg) {
        const int m = by * GBM + wr * 64 + i * 16 + fq * 4 + rg;
        const int n = bx * GBN + wc * 64 + j * 16 + fn;
        hib[(size_t)m * VOC + n] = f32_to_bf16(acc[i][j][rg]);
      }
}

// ---------------- 2b) fallback f32 tiled GEMM (binning proxy) ----------------
#define BM 64
#define BN 64
#define BK 16
__global__ __launch_bounds__(256) void k_score(const float* __restrict__ A,
                                               const float* __restrict__ B,
                                               float* __restrict__ hi) {
  __shared__ float As[BK][BM];
  __shared__ float Bs[BK][BN];
  const int t  = threadIdx.x;
  const int tx = t & 15, ty = t >> 4;
  const int bx = blockIdx.x, by = blockIdx.y;
  const int arow = t >> 2, acg = t & 3;
  const int brow = t >> 4, bcg = t & 15;
  const float* Ap = A + (size_t)(by * BM + arow) * HID + acg * 4;
  const float* Bp = B + (size_t)brow * VOC + (size_t)bx * BN + bcg * 4;

  float acc[4][4] = {};
  for (int k0 = 0; k0 < HID; k0 += BK) {
    const float4 av = *(const float4*)(Ap + k0);
    const float4 bv = *(const float4*)(Bp + (size_t)k0 * VOC);
    As[acg * 4 + 0][arow] = av.x;
    As[acg * 4 + 1][arow] = av.y;
    As[acg * 4 + 2][arow] = av.z;
    As[acg * 4 + 3][arow] = av.w;
    *(float4*)&Bs[brow][bcg * 4] = bv;
    __syncthreads();
#pragma unroll
    for (int kk = 0; kk < BK; ++kk) {
      const float4 af = *(const float4*)&As[kk][ty * 4];
      const float4 bf = *(const float4*)&Bs[kk][tx * 4];
#pragma unroll
      for (int i = 0; i < 4; ++i) {
        const float a = (&af.x)[i];
        acc[i][0] += a * bf.x; acc[i][1] += a * bf.y;
        acc[i][2] += a * bf.z; acc[i][3] += a * bf.w;
      }
    }
    __syncthreads();
  }
  const size_t colbase = (size_t)bx * BN + tx * 4;
#pragma unroll
  for (int i = 0; i < 4; ++i) {
    const size_t row = (size_t)by * BM + ty * 4 + i;
    *(float4*)(hi + row * VOC + colbase) =
        make_float4(acc[i][0], acc[i][1], acc[i][2], acc[i][3]);
  }
}

// ---------------- XLA/Eigen f32 fast-tanh (verified r5) ----------------------
__device__ __forceinline__ float tanh_xla(float x) {
  const float ax = fabsf(x);
  const float cx = fminf(fmaxf(x, -9.0f), 9.0f);
  const float x2 = cx * cx;
  float p = -2.76076847742355e-16f;
  p = fmaf(x2, p, 2.00018790482477e-13f);
  p = fmaf(x2, p, -8.60467152213735e-11f);
  p = fmaf(x2, p, 5.12229709037114e-08f);
  p = fmaf(x2, p, 1.48572235717979e-05f);
  p = fmaf(x2, p, 6.37261928875436e-04f);
  p = fmaf(x2, p, 4.89352455891786e-03f);
  p = cx * p;
  float q = 1.19825839466702e-06f;
  q = fmaf(x2, q, 1.18534705686654e-04f);
  q = fmaf(x2, q, 2.26843463243900e-03f);
  q = fmaf(x2, q, 4.89352518554385e-03f);
  const float r = p / q;
  return (ax < 0.0004f) ? x : r;
}

__device__ __forceinline__ unsigned sortable_u32(float x) {
  unsigned u = __float_as_uint(x);
  return (u & 0x80000000u) ? ~u : (u | 0x80000000u);
}
__device__ __forceinline__ unsigned sortable_u16(unsigned short u) {
  return (u & 0x8000u) ? (unsigned)(unsigned short)~u : (unsigned)(u | 0x8000u);
}

// ------- 3) per-row top-300: bin proxy, rescore exact chain, sort ------------
template <int BF16HI>
__global__ __launch_bounds__(512) void k_topk(const float* __restrict__ hs,
                                              const float* __restrict__ Wb,
                                              const float* __restrict__ WbT,
                                              const void* __restrict__ hiv,
                                              float* __restrict__ oidx) {
  const int r = blockIdx.x;
  const int t = threadIdx.x;

  __shared__ unsigned hist[NBINS];
  __shared__ unsigned partial[512];
  __shared__ float    hrow[HID];
  __shared__ float    vals[CAP];
  __shared__ int      idxs[CAP];
  __shared__ unsigned cnt;
  __shared__ int      bLo_s;

  hrow[t] = hs[(size_t)r * HID + t];
  for (int i = t; i < NBINS; i += 512) hist[i] = 0u;
  if (t == 0) cnt = 0u;
  __syncthreads();

  if (BF16HI) {
    const u16x8* rh8 = (const u16x8*)((const unsigned short*)hiv + (size_t)r * VOC);
    for (int i = t; i < VOC / 8; i += 512) {
      const u16x8 v = rh8[i];
#pragma unroll
      for (int j = 0; j < 8; ++j) atomicAdd(&hist[sortable_u16(v[j]) >> 3], 1u);
    }
  } else {
    const float4* rh4 = (const float4*)((const float*)hiv + (size_t)r * VOC);
    for (int i = t; i < VOC / 4; i += 512) {
      const float4 v = rh4[i];
      atomicAdd(&hist[sortable_u32(v.x) >> 19], 1u);
      atomicAdd(&hist[sortable_u32(v.y) >> 19], 1u);
      atomicAdd(&hist[sortable_u32(v.z) >> 19], 1u);
      atomicAdd(&hist[sortable_u32(v.w) >> 19], 1u);
    }
  }
  __syncthreads();

  // suffix scan over 512 chunks of 16 bins
  unsigned psum = 0;
#pragma unroll
  for (int i = 0; i < NBINS / 512; ++i) psum += hist[t * (NBINS / 512) + i];
  partial[t] = psum;
  __syncthreads();
  for (int off = 1; off < 512; off <<= 1) {
    const unsigned add = (t + off < 512) ? partial[t + off] : 0u;
    __syncthreads();
    partial[t] += add;
    __syncthreads();
  }
  const unsigned above = partial[t] - psum;
  if (above < TOPK && partial[t] >= TOPK) {  // exactly one crossing chunk
    unsigned c = above;
    int b = t * (NBINS / 512);
    for (int i = NBINS / 512 - 1; i >= 0; --i) {
      c += hist[t * (NBINS / 512) + i];
      if (c >= TOPK) { b = t * (NBINS / 512) + i; break; }
    }
    int bl = b;
    unsigned tot = c;
#pragma unroll
    for (int s = 0; s < 3; ++s)   // 3 safety bins: covers proxy-vs-chain error
      if (bl > 0 && tot + hist[bl - 1] <= (unsigned)CAP) { tot += hist[bl - 1]; --bl; }
    bLo_s = bl;
  }
  __syncthreads();
  const int bLo = bLo_s;

  // collect candidate indices
  if (BF16HI) {
    const u16x8* rh8 = (const u16x8*)((const unsigned short*)hiv + (size_t)r * VOC);
    for (int i = t; i < VOC / 8; i += 512) {
      const u16x8 v = rh8[i];
#pragma unroll
      for (int j = 0; j < 8; ++j)
        if ((int)(sortable_u16(v[j]) >> 3) >= bLo) {
          const unsigned p = atomicAdd(&cnt, 1u);
          if (p < CAP) idxs[p] = i * 8 + j;
        }
    }
  } else {
    const float* rh = (const float*)hiv + (size_t)r * VOC;
    for (int v = t; v < VOC; v += 512)
      if ((int)(sortable_u32(rh[v]) >> 19) >= bLo) {
        const unsigned p = atomicAdd(&cnt, 1u);
        if (p < CAP) idxs[p] = v;
      }
  }
  __syncthreads();
  const int n = (int)min(cnt, (unsigned)CAP);

  // EXACT rescore: ascending-h single-accumulator fmaf chain + double f32 tanh
  // (bit-matches the reference; verified round 5 — do not alter)
  for (int k = t; k < n; k += 512) {
    const int c = idxs[k];
    float acc = 0.0f;
    if (WbT) {
      const float* ww = WbT + (size_t)c * HID;
      for (int h = 0; h < HID; ++h) acc = fmaf(hrow[h], ww[h], acc);
    } else {
      for (int h = 0; h < HID; ++h) acc = fmaf(hrow[h], Wb[(size_t)h * VOC + c], acc);
    }
    vals[k] = tanh_xla(tanh_xla(acc));
  }
  __syncthreads();
  for (int i = t; i < CAP; i += 512)
    if (i >= n) { vals[i] = -3.0e38f; idxs[i] = 0x7FFFFFFF; }
  __syncthreads();

  // bitonic sort: y desc, tie -> lower index
  for (int k = 2; k <= CAP; k <<= 1) {
    for (int j = k >> 1; j > 0; j >>= 1) {
      for (int i = t; i < CAP; i += 512) {
        const int l = i ^ j;
        if (l > i) {
          const float vi = vals[i], vl = vals[l];
          const int   ii = idxs[i], il = idxs[l];
          const bool up = ((i & k) == 0);
          const bool lBetter = (vl > vi) || (vl == vi && il < ii);
          const bool iBetter = (vi > vl) || (vi == vl && ii < il);
          if (up ? lBetter : iBetter) {
            vals[i] = vl; vals[l] = vi;
            idxs[i] = il; idxs[l] = ii;
          }
        }
      }
      __syncthreads();
    }
  }
  for (int j = t; j < TOPK; j += 512)
    oidx[(size_t)r * TOPK + j] = (float)idxs[j];
}

// ------- 4) zero row, compute candidate logits vs W_out (f64), scatter -------
__global__ __launch_bounds__(256) void k_scatter(const float* __restrict__ hs,
                                                 const float* __restrict__ wout,
                                                 const float* __restrict__ woutT,
                                                 const float* __restrict__ oidx,
                                                 float* __restrict__ out) {
  const int r = blockIdx.x;
  const int t = threadIdx.x;
  __shared__ float hrow[HID];
  __shared__ int   cidx[TOPK];
  __shared__ float cval[TOPK];

  for (int i = t; i < HID; i += 256) hrow[i] = hs[(size_t)r * HID + i];
  for (int i = t; i < TOPK; i += 256) cidx[i] = (int)(oidx[(size_t)r * TOPK + i] + 0.5f);
  __syncthreads();

  float* orow = out + (size_t)r * VOC;
  const float4 z4 = make_float4(0.f, 0.f, 0.f, 0.f);
  for (int i = t; i < VOC / 4; i += 256) ((float4*)orow)[i] = z4;

  const int lane = t & 63, wave = t >> 6;
  double ha[8];
#pragma unroll
  for (int u = 0; u < 8; ++u) ha[u] = (double)hrow[lane * 8 + u];

  for (int k = wave; k < TOPK; k += 4) {
    const int c = cidx[k];
    double s = 0.0;
    if (woutT) {
      const float4* col = (const float4*)(woutT + (size_t)c * HID + lane * 8);
      const float4 w0 = col[0], w1 = col[1];
      s = ha[0] * (double)w0.x + ha[1] * (double)w0.y + ha[2] * (double)w0.z + ha[3] * (double)w0.w
        + ha[4] * (double)w1.x + ha[5] * (double)w1.y + ha[6] * (double)w1.z + ha[7] * (double)w1.w;
    } else {
#pragma unroll
      for (int u = 0; u < 8; ++u)
        s += ha[u] * (double)wout[(size_t)(lane * 8 + u) * VOC + c];
    }
#pragma unroll
    for (int off = 32; off > 0; off >>= 1) s += __shfl_down(s, off);
    if (lane == 0) cval[k] = (float)s;
  }
  __syncthreads();
  for (int j = t; j < TOPK; j += 256) orow[cidx[j]] = cval[j];
}

// -----------------------------------------------------------------------------
extern "C" void kernel_launch(void* const* d_in, const int* in_sizes, int n_in,
                              void* d_out, int out_size, void* d_ws, size_t ws_size,
                              hipStream_t stream) {
  const float* hs    = (const float*)d_in[0];
  const float* W_out = (const float*)d_in[1];
  const float* W_bin = (const float*)d_in[2];
  float* out  = (float*)d_out;
  float* oidx = out + (size_t)RROWS * VOC;

  // ws layout (priority preserves round-5 behavior if ws is small):
  // [wbT f32 65.5MB][woT f32 65.5MB][wbTb bf16 32.8MB][hsb bf16 4.2MB]
  const size_t nWT = (size_t)VOC * HID;            // 16,384,000
  char* wsc = (char*)d_ws;
  size_t off = 0;
  float* wbT = nullptr; float* woT = nullptr;
  unsigned short* wbTb = nullptr; unsigned short* hsb = nullptr;
  if (ws_size >= off + nWT * 4) { wbT  = (float*)(wsc + off); off += nWT * 4; }
  if (ws_size >= off + nWT * 4) { woT  = (float*)(wsc + off); off += nWT * 4; }
  if (ws_size >= off + nWT * 2) { wbTb = (unsigned short*)(wsc + off); off += nWT * 2; }
  const size_t nHS = (size_t)RROWS * HID;          // 2,097,152
  if (ws_size >= off + nHS * 2) { hsb  = (unsigned short*)(wsc + off); off += nHS * 2; }

  if (wbT) k_transpose<<<dim3(VOC / 32, HID / 32), dim3(32, 8), 0, stream>>>(W_bin, wbT);
  if (woT) k_transpose<<<dim3(VOC / 32, HID / 32), dim3(32, 8), 0, stream>>>(W_out, woT);

  const bool mfma = (wbT != nullptr) && (wbTb != nullptr) && (hsb != nullptr);
  if (mfma) {
    k_cvt<<<(int)((nWT / 4 + 255) / 256), 256, 0, stream>>>(wbT, wbTb, (int)(nWT / 4));
    k_cvt<<<(int)((nHS / 4 + 255) / 256), 256, 0, stream>>>(hs, hsb, (int)(nHS / 4));
    unsigned short* hib = (unsigned short*)d_out;  // bf16 proxy plane (262 MB)
    k_score_mfma<<<dim3(VOC / GBN, RROWS / GBM), 256, 0, stream>>>(hsb, wbTb, hib);
    k_topk<1><<<RROWS, 512, 0, stream>>>(hs, W_bin, wbT, hib, oidx);
  } else {
    float* hi = out;                               // f32 proxy plane (524 MB)
    k_score<<<dim3(VOC / BN, RROWS / BM), 256, 0, stream>>>(hs, W_bin, hi);
    k_topk<0><<<RROWS, 512, 0, stream>>>(hs, W_bin, wbT, hi, oidx);
  }
  k_scatter<<<RROWS, 256, 0, stream>>>(hs, W_out, woT, oidx, out);
}